// Round 7
// baseline (522.473 us; speedup 1.0000x reference)
//
#include <hip/hip_runtime.h>
#include <math.h>

#define BATCH  8192
#define TSTEPS 50
#define WPB    2           // waves per block (disjoint LDS slices, no cross-wave traffic)
#define PPW    5           // points per wave (15 cols + 1 dead)
#define KSTR   168         // Pw row stride (bf16)
#define GKSTR  160         // global Wb row stride (bf16, 144 real + 16 zero)
#define TABSTR 100         // tabs row stride (f32)
#define PI_F   3.14159265358979323846f

typedef __bf16 bf16x8 __attribute__((ext_vector_type(8)));
typedef float  f32x4  __attribute__((ext_vector_type(4)));

__device__ __forceinline__ void lds_fence() {
    // same-wave LDS RAW fence (r1-proven); consumers are ds ops -> "memory" orders them
    asm volatile("s_waitcnt lgkmcnt(0)" ::: "memory");
}

__device__ __forceinline__ unsigned pack2bf(float a, float b) {
    unsigned short ua = __builtin_bit_cast(unsigned short, (__bf16)a);
    unsigned short ub = __builtin_bit_cast(unsigned short, (__bf16)b);
    return (unsigned)ua | ((unsigned)ub << 16);
}

// ---------------- precompute: L, spectral-scaled W in bf16 (rows=(d,i), cols=(j,k)) ----------------
__global__ void precompute_kernel(const float* __restrict__ beta,
                                  const float* __restrict__ ls,
                                  const float* __restrict__ basis,
                                  unsigned short* __restrict__ Wb,
                                  float* __restrict__ auxg)
{
    __shared__ float red[256];
    __shared__ float Ls[3], W1s[3];
    int t = threadIdx.x;

    for (int d = 0; d < 3; ++d) {
        red[t] = fabsf(basis[t*3 + d]);
        __syncthreads();
        for (int s = 128; s > 0; s >>= 1) {
            if (t < s) red[t] = fmaxf(red[t], red[t+s]);
            __syncthreads();
        }
        if (t == 0) {
            float L = 1.5f * red[0];
            Ls[d]  = L;
            W1s[d] = PI_F / (2.0f * L);
        }
        __syncthreads();
    }

    float pref[6], l20[6], l21[6], l22[6];
    #pragma unroll
    for (int dd = 0; dd < 6; ++dd) {
        float a = ls[dd*3+0], b = ls[dd*3+1], c = ls[dd*3+2];
        pref[dd] = 3.9685803f * sqrtf(a*b*c);   // (2*pi)^(3/4) * sqrt(prod ls)
        l20[dd] = a*a; l21[dd] = b*b; l22[dd] = c*c;
    }

    for (int idx = t; idx < 96*GKSTR; idx += 256) {
        int n = idx / GKSTR, k = idx - n*GKSTR;
        int d = n >> 4, i = n & 15;
        float v = 0.0f;
        if (i < 12 && k < 144) {
            int j = k / 12, kk = k - (k/12)*12;
            float o0 = W1s[0]*(float)(i+1);
            float o1 = W1s[1]*(float)(j+1);
            float o2 = W1s[2]*(float)(kk+1);
            float e = expf(-0.25f*(o0*o0*l20[d] + o1*o1*l21[d] + o2*o2*l22[d]));
            v = beta[d*1728 + i*144 + k] * pref[d] * e;
        }
        Wb[idx] = __builtin_bit_cast(unsigned short, (__bf16)v);
    }

    if (t < 3) {
        auxg[t]     = Ls[t];
        auxg[3 + t] = W1s[t];
        auxg[6 + t] = 1.0f / sqrtf(Ls[t]);
    }
}

// ---------------- main fused RK4 integrator: wave-autonomous, zero block barriers ----------------
// wave owns 5 points; cols 0..14 = (pt,path), col 15 dead (Pw row 15 = zeros).
// W (all 96 M-rows) lives in wfrag[6][5] registers for the whole kernel.
__global__ void __launch_bounds__(64*WPB, 2) geodesic_kernel(
    const float* __restrict__ pos0, const float* __restrict__ vel0,
    const unsigned short* __restrict__ Wbg, const float* __restrict__ auxg,
    float* __restrict__ out)
{
    __shared__ __align__(16) __bf16 Pw[WPB][16*KSTR];       // 2 x 5.25 KB
    __shared__ __align__(16) float tabsw[WPB][PPW][TABSTR]; // 2 x 2.0 KB
    __shared__ __align__(16) float scrw[WPB][16][12];       // 2 x 768 B
    __shared__ float qsw[WPB][PPW][4];                      // 2 x 80 B

    const int tid  = threadIdx.x;
    const int wib  = tid >> 6, lane = tid & 63;

    // one-time zero init of this wave's slices (pads must be 0, row15 stays 0)
    {
        unsigned* pz = (unsigned*)&Pw[wib][0];
        for (int i = lane; i < 16*KSTR/2; i += 64) pz[i] = 0u;
        float* tz = &tabsw[wib][0][0];
        for (int i = lane; i < PPW*TABSTR; i += 64) tz[i] = 0.f;
    }

    const float L0 = auxg[0], L1 = auxg[1], L2 = auxg[2];
    const float w10 = auxg[3], w11 = auxg[4], w12 = auxg[5];
    const float isq0 = auxg[6], isq1 = auxg[7], isq2 = auxg[8];

    const int lrow = lane & 15, lkg = lane >> 4;
    const int ptl0 = lrow / 3;
    const int ptl  = (ptl0 > 4) ? 4 : ptl0;   // lrow 15 -> duplicate of pt 4 (harmless)
    const int pn   = lrow - 3*ptl0;

    // W fragments: all 6 M-tiles x 5 K-steps, resident in regs forever (120 VGPR)
    bf16x8 wfrag[6][5];
    {
        const __bf16* Wb = (const __bf16*)Wbg;
        #pragma unroll
        for (int mt = 0; mt < 6; ++mt)
            #pragma unroll
            for (int ks = 0; ks < 5; ++ks)
                wfrag[mt][ks] = *(const bf16x8*)(Wb + (mt*16 + lrow)*GKSTR + ks*32 + lkg*8);
    }

    const int wid = blockIdx.x*WPB + wib;
    const int ptg = wid*PPW + ptl;
    const bool valid = (ptg < BATCH);
    const int  ptc = valid ? ptg : (BATCH-1);
    const size_t pg3 = (size_t)ptg*3;

    float px = pos0[ptc*3+0], py = pos0[ptc*3+1], pz = pos0[ptc*3+2];
    float vx = vel0[ptc*3+0], vy = vel0[ptc*3+1], vz = vel0[ptc*3+2];
    float vcx = vx, vcy = vy, vcz = vz;

    const bool qwriter = (pn == 0 && lkg == 0 && lrow < 15);

    if (qwriter) {
        qsw[wib][ptl][0] = px; qsw[wib][ptl][1] = py; qsw[wib][ptl][2] = pz;
        if (valid) {
            out[pg3+0] = px; out[pg3+1] = py; out[pg3+2] = pz;
            out[(size_t)BATCH*3 + pg3 + 0] = vx;
            out[(size_t)BATCH*3 + pg3 + 1] = vy;
            out[(size_t)BATCH*3 + pg3 + 2] = vz;
        }
    }
    lds_fence();   // zero-init + qs visible to own wave

    const float dt  = 1.0f/49.0f;
    const float hdt = 0.5f/49.0f;
    const float sdt = dt/6.0f;

    #pragma unroll 1
    for (int step = 0; step < TSTEPS-1; ++step) {
        float vsx=0,vsy=0,vsz=0, asx=0,asy=0,asz=0;

        #pragma unroll 1
        for (int s = 0; s < 4; ++s) {
            // ---- P0: trig tables (180 sincos units over 64 lanes)
            #pragma unroll 1
            for (int u = lane; u < 180; u += 64) {
                int pt = u / 36;
                int r  = u - 36*pt;
                int d  = (r < 12) ? 0 : ((r < 24) ? 1 : 2);
                int k  = r - 12*d;
                float q   = qsw[wib][pt][d];
                float Ld  = (d==0)?L0:((d==1)?L1:L2);
                float w1d = (d==0)?w10:((d==1)?w11:w12);
                float isd = (d==0)?isq0:((d==1)?isq1:isq2);
                float wk = w1d * (float)(k+1);
                float sn, cs;
                __sincosf(wk*(q + Ld), &sn, &cs);
                int offs = (d==0)?0:((d==1)?32:56);
                int offc = offs + ((d==0)?16:12);
                tabsw[wib][pt][offs+k] = isd*sn;
                tabsw[wib][pt][offc+k] = isd*cs*wk;
            }
            lds_fence();

            // ---- P1: pair products -> Pw (120 units over 64 lanes)
            #pragma unroll 1
            for (int v = lane; v < 120; v += 64) {
                int pt = v / 24;
                int role = v - 24*pt;
                int j = role >> 1, kb = (role & 1)*6;
                const float* tb = &tabsw[wib][pt][0];
                float s1 = tb[32+j], c1 = tb[44+j];
                float2 sa = *(const float2*)&tb[56+kb];
                float2 sb = *(const float2*)&tb[58+kb];
                float2 sg = *(const float2*)&tb[60+kb];
                float2 ca = *(const float2*)&tb[68+kb];
                float2 cb = *(const float2*)&tb[70+kb];
                float2 cg = *(const float2*)&tb[72+kb];
                float s2v[6] = {sa.x, sa.y, sb.x, sb.y, sg.x, sg.y};
                float c2v[6] = {ca.x, ca.y, cb.x, cb.y, cg.x, cg.y};
                int colb = j*12 + kb;
                unsigned* pss = (unsigned*)&Pw[wib][(pt*3 + 0)*KSTR + colb];
                unsigned* pcs = (unsigned*)&Pw[wib][(pt*3 + 1)*KSTR + colb];
                unsigned* psc = (unsigned*)&Pw[wib][(pt*3 + 2)*KSTR + colb];
                #pragma unroll
                for (int u2 = 0; u2 < 3; ++u2) {
                    pss[u2] = pack2bf(s1*s2v[2*u2], s1*s2v[2*u2+1]);
                    pcs[u2] = pack2bf(c1*s2v[2*u2], c1*s2v[2*u2+1]);
                    psc[u2] = pack2bf(s1*c2v[2*u2], s1*c2v[2*u2+1]);
                }
            }
            lds_fence();

            // ---- P2: GEMM  C[(d,i), col] = W x P   (6 M-tiles, 5 K-steps)
            f32x4 acc0={0.f,0.f,0.f,0.f}, acc1=acc0, acc2=acc0, acc3=acc0, acc4=acc0, acc5=acc0;
            {
                const __bf16* prow = &Pw[wib][lrow*KSTR];
                #pragma unroll
                for (int ks = 0; ks < 5; ++ks) {
                    bf16x8 pf = *(const bf16x8*)(prow + ks*32 + lkg*8);
                    acc0 = __builtin_amdgcn_mfma_f32_16x16x32_bf16(wfrag[0][ks], pf, acc0, 0, 0, 0);
                    acc1 = __builtin_amdgcn_mfma_f32_16x16x32_bf16(wfrag[1][ks], pf, acc1, 0, 0, 0);
                    acc2 = __builtin_amdgcn_mfma_f32_16x16x32_bf16(wfrag[2][ks], pf, acc2, 0, 0, 0);
                    acc3 = __builtin_amdgcn_mfma_f32_16x16x32_bf16(wfrag[3][ks], pf, acc3, 0, 0, 0);
                    acc4 = __builtin_amdgcn_mfma_f32_16x16x32_bf16(wfrag[4][ks], pf, acc4, 0, 0, 0);
                    acc5 = __builtin_amdgcn_mfma_f32_16x16x32_bf16(wfrag[5][ks], pf, acc5, 0, 0, 0);
                }
            }

            // ---- stage-2: i-contraction (i = lkg*4+r), butterfly over lkg, write scr
            {
                f32x4 s0v = *(const f32x4*)&tabsw[wib][ptl][lkg*4];
                f32x4 c0v = *(const f32x4*)&tabsw[wib][ptl][16 + lkg*4];
                float vs0 = acc0[0]*s0v[0] + acc0[1]*s0v[1] + acc0[2]*s0v[2] + acc0[3]*s0v[3];
                float vs1 = acc1[0]*s0v[0] + acc1[1]*s0v[1] + acc1[2]*s0v[2] + acc1[3]*s0v[3];
                float vs2 = acc2[0]*s0v[0] + acc2[1]*s0v[1] + acc2[2]*s0v[2] + acc2[3]*s0v[3];
                float vs3 = acc3[0]*s0v[0] + acc3[1]*s0v[1] + acc3[2]*s0v[2] + acc3[3]*s0v[3];
                float vs4 = acc4[0]*s0v[0] + acc4[1]*s0v[1] + acc4[2]*s0v[2] + acc4[3]*s0v[3];
                float vs5 = acc5[0]*s0v[0] + acc5[1]*s0v[1] + acc5[2]*s0v[2] + acc5[3]*s0v[3];
                float vc0 = acc0[0]*c0v[0] + acc0[1]*c0v[1] + acc0[2]*c0v[2] + acc0[3]*c0v[3];
                float vc1 = acc1[0]*c0v[0] + acc1[1]*c0v[1] + acc1[2]*c0v[2] + acc1[3]*c0v[3];
                float vc2 = acc2[0]*c0v[0] + acc2[1]*c0v[1] + acc2[2]*c0v[2] + acc2[3]*c0v[3];
                float vc3 = acc3[0]*c0v[0] + acc3[1]*c0v[1] + acc3[2]*c0v[2] + acc3[3]*c0v[3];
                float vc4 = acc4[0]*c0v[0] + acc4[1]*c0v[1] + acc4[2]*c0v[2] + acc4[3]*c0v[3];
                float vc5 = acc5[0]*c0v[0] + acc5[1]*c0v[1] + acc5[2]*c0v[2] + acc5[3]*c0v[3];

                vs0 += __shfl_xor(vs0,16); vs0 += __shfl_xor(vs0,32);
                vs1 += __shfl_xor(vs1,16); vs1 += __shfl_xor(vs1,32);
                vs2 += __shfl_xor(vs2,16); vs2 += __shfl_xor(vs2,32);
                vs3 += __shfl_xor(vs3,16); vs3 += __shfl_xor(vs3,32);
                vs4 += __shfl_xor(vs4,16); vs4 += __shfl_xor(vs4,32);
                vs5 += __shfl_xor(vs5,16); vs5 += __shfl_xor(vs5,32);
                vc0 += __shfl_xor(vc0,16); vc0 += __shfl_xor(vc0,32);
                vc1 += __shfl_xor(vc1,16); vc1 += __shfl_xor(vc1,32);
                vc2 += __shfl_xor(vc2,16); vc2 += __shfl_xor(vc2,32);
                vc3 += __shfl_xor(vc3,16); vc3 += __shfl_xor(vc3,32);
                vc4 += __shfl_xor(vc4,16); vc4 += __shfl_xor(vc4,32);
                vc5 += __shfl_xor(vc5,16); vc5 += __shfl_xor(vc5,32);

                if (lkg == 0) {
                    float* sr = &scrw[wib][lrow][0];
                    sr[0]=vs0; sr[1]=vs1; sr[2]=vs2; sr[3]=vs3; sr[4]=vs4; sr[5]=vs5;
                    sr[6]=vc0; sr[7]=vc1; sr[8]=vc2; sr[9]=vc3; sr[10]=vc4; sr[11]=vc5;
                }
            }
            lds_fence();

            // ---- exchange + epilogue (redundant per lane; identical -> deterministic)
            float ax, ay, az;
            {
                const float* s0p = &scrw[wib][3*ptl    ][0];
                const float* s1p = &scrw[wib][3*ptl + 1][0];
                const float* s2p = &scrw[wib][3*ptl + 2][0];
                f32x4 a0 = *(const f32x4*)&s0p[0];
                f32x4 a1 = *(const f32x4*)&s0p[4];
                f32x4 a2 = *(const f32x4*)&s0p[8];
                f32x4 b0 = *(const f32x4*)&s1p[0];
                float2 b1 = *(const float2*)&s1p[4];
                f32x4 c0 = *(const f32x4*)&s2p[0];
                float2 c1x = *(const float2*)&s2p[4];

                float ux = vcx, uy = vcy, uz = vcz;

                float g00 = a0[0]+1.f, g10 = a0[1], g11 = a0[2]+1.f;
                float g20 = a0[3], g21 = a1[0], g22 = a1[1]+1.f;
                float d0a0=a1[2], d0a1=a1[3], d0a2=a2[0], d0a3=a2[1], d0a4=a2[2], d0a5=a2[3];
                float d1a0=b0[0], d1a1=b0[1], d1a2=b0[2], d1a3=b0[3], d1a4=b1.x, d1a5=b1.y;
                float d2a0=c0[0], d2a1=c0[1], d2a2=c0[2], d2a3=c0[3], d2a4=c1x.x, d2a5=c1x.y;

                float A00 = g11*g22 - g21*g21;
                float A01 = g20*g21 - g10*g22;
                float A02 = g10*g21 - g20*g11;
                float A11 = g00*g22 - g20*g20;
                float A12 = g10*g20 - g00*g21;
                float A22 = g00*g11 - g10*g10;
                float det = g00*A00 + g10*A01 + g20*A02;
                float inv = 1.0f / det;
                float h00=A00*inv, h01=A01*inv, h02=A02*inv;
                float h11=A11*inv, h12=A12*inv, h22=A22*inv;

                float t0 = ux*d0a0 + uy*d1a0 + uz*d2a0;
                float t1 = ux*d0a1 + uy*d1a1 + uz*d2a1;
                float t2 = ux*d0a2 + uy*d1a2 + uz*d2a2;
                float t3 = ux*d0a3 + uy*d1a3 + uz*d2a3;
                float t4 = ux*d0a4 + uy*d1a4 + uz*d2a4;
                float t5 = ux*d0a5 + uy*d1a5 + uz*d2a5;

                float hl0 = ux*t0 + uy*t1 + uz*t3;
                float hl1 = ux*t1 + uy*t2 + uz*t4;
                float hl2 = ux*t3 + uy*t4 + uz*t5;

                float xx = ux*ux, yy = uy*uy, zz = uz*uz;
                float xy2 = 2.f*ux*uy, xz2 = 2.f*ux*uz, yz2 = 2.f*uy*uz;
                float e0 = xx*d0a0 + xy2*d0a1 + yy*d0a2 + xz2*d0a3 + yz2*d0a4 + zz*d0a5;
                float e1 = xx*d1a0 + xy2*d1a1 + yy*d1a2 + xz2*d1a3 + yz2*d1a4 + zz*d1a5;
                float e2 = xx*d2a0 + xy2*d2a1 + yy*d2a2 + xz2*d2a3 + yz2*d2a4 + zz*d2a5;

                float C0 = hl0 - 0.5f*e0;
                float C1 = hl1 - 0.5f*e1;
                float C2 = hl2 - 0.5f*e2;
                ax = -(h00*C0 + h01*C1 + h02*C2);
                ay = -(h01*C0 + h11*C1 + h12*C2);
                az = -(h02*C0 + h12*C1 + h22*C2);
            }

            // ---- RK4 bookkeeping (all lanes, replicated per point)
            {
                const float wgt = (s == 1 || s == 2) ? 2.f : 1.f;
                vsx += wgt*vcx; vsy += wgt*vcy; vsz += wgt*vcz;
                asx += wgt*ax;  asy += wgt*ay;  asz += wgt*az;

                if (s < 3) {
                    const float c = (s == 2) ? dt : hdt;
                    float qnx = fmaf(c, vcx, px);
                    float qny = fmaf(c, vcy, py);
                    float qnz = fmaf(c, vcz, pz);
                    vcx = fmaf(c, ax, vx);
                    vcy = fmaf(c, ay, vy);
                    vcz = fmaf(c, az, vz);
                    if (qwriter) {
                        qsw[wib][ptl][0] = qnx; qsw[wib][ptl][1] = qny; qsw[wib][ptl][2] = qnz;
                    }
                } else {
                    px = fmaf(sdt, vsx, px);
                    py = fmaf(sdt, vsy, py);
                    pz = fmaf(sdt, vsz, pz);
                    vx = fmaf(sdt, asx, vx);
                    vy = fmaf(sdt, asy, vy);
                    vz = fmaf(sdt, asz, vz);
                    vcx = vx; vcy = vy; vcz = vz;
                    if (qwriter) {
                        qsw[wib][ptl][0] = px; qsw[wib][ptl][1] = py; qsw[wib][ptl][2] = pz;
                        if (valid) {
                            size_t ob = (size_t)(step+1) * 2u * BATCH * 3u;
                            out[ob + pg3 + 0] = px;
                            out[ob + pg3 + 1] = py;
                            out[ob + pg3 + 2] = pz;
                            out[ob + (size_t)BATCH*3 + pg3 + 0] = vx;
                            out[ob + (size_t)BATCH*3 + pg3 + 1] = vy;
                            out[ob + (size_t)BATCH*3 + pg3 + 2] = vz;
                        }
                    }
                }
            }
            lds_fence();   // qs ready for next eval's trig
        }
    }
}

extern "C" void kernel_launch(void* const* d_in, const int* in_sizes, int n_in,
                              void* d_out, int out_size, void* d_ws, size_t ws_size,
                              hipStream_t stream) {
    (void)in_sizes; (void)n_in; (void)out_size; (void)ws_size;
    const float* pos0  = (const float*)d_in[0];
    const float* vel0  = (const float*)d_in[1];
    const float* beta  = (const float*)d_in[2];
    const float* ls    = (const float*)d_in[3];
    const float* basis = (const float*)d_in[4];
    float* outp = (float*)d_out;

    unsigned short* Wb = (unsigned short*)d_ws;                 // 96*160 bf16
    float* auxg = (float*)((char*)d_ws + 96*GKSTR*sizeof(unsigned short));

    precompute_kernel<<<1, 256, 0, stream>>>(beta, ls, basis, Wb, auxg);
    const int nblk = (BATCH + WPB*PPW - 1) / (WPB*PPW);         // 820
    geodesic_kernel<<<nblk, 64*WPB, 0, stream>>>(pos0, vel0, Wb, auxg, outp);
}